// Round 2
// baseline (221.216 us; speedup 1.0000x reference)
//
#include <hip/hip_runtime.h>

#define B_  32
#define C_  256
#define H_  56
#define W_  56
#define HW  3136      // H_*W_
#define KK  9
#define NPLANES (B_*C_)   // 8192

typedef float v4f __attribute__((ext_vector_type(4)));

// ---------------------------------------------------------------------------
// Kernel 1: global average pool. One WAVE per (b,c) plane, 4 planes/block.
// Pure shuffle reduction; regular loads keep x resident in L3 for dconv.
// At the HBM read floor (~17 us) — unchanged.
// ---------------------------------------------------------------------------
__global__ __launch_bounds__(256) void pool_kernel(const float* __restrict__ x,
                                                   float* __restrict__ pooled) {
    const int wid  = threadIdx.x >> 6;
    const int lane = threadIdx.x & 63;
    const int plane = blockIdx.x * 4 + wid;             // 2048 blocks * 4 waves
    const float4* xp = (const float4*)(x + (size_t)plane * HW);

    float s = 0.f;
    #pragma unroll
    for (int k = 0; k < 12; ++k) {                      // 12*64 = 768 strips
        float4 v = xp[lane + k * 64];
        s += (v.x + v.y) + (v.z + v.w);
    }
    if (lane < 16) {                                    // remainder 768..783
        float4 v = xp[768 + lane];
        s += (v.x + v.y) + (v.z + v.w);
    }
    #pragma unroll
    for (int off = 32; off > 0; off >>= 1)
        s += __shfl_down(s, off, 64);
    if (lane == 0)
        pooled[plane] = s * (1.0f / (float)HW);
}

// ---------------------------------------------------------------------------
// Kernel 2: LDS-free register stencil.
//   * kerngen (threads 0..143) -> 9 taps in 36B LDS, ONE barrier. Unchanged
//     from the verified round-0 version.
//   * x is NOT staged: each 2x4 output tile reads its 4 input rows straight
//     from global (dwordx4 + 2 scalar halos per row). Overlap between
//     neighboring lanes/tiles hits L1/L2; the plane itself is L3-resident
//     from the pool pass.
//   * No ds_write/ds_read of x, no vmcnt(0)-before-stage, one barrier fewer.
//     Live registers ~40 -> __launch_bounds__(256,8): 8 blocks/CU (32 waves)
//     vs 4 before, doubling latency-hiding.
// ---------------------------------------------------------------------------
__global__ __launch_bounds__(256, 8) void dconv_kernel(const float* __restrict__ x,
                                                       const float* __restrict__ pooled,
                                                       const float* __restrict__ Wk,
                                                       const float* __restrict__ bk,
                                                       float* __restrict__ out) {
    const int plane = blockIdx.x;                       // b*C_ + c
    const int b = plane >> 8;
    const int c = plane & 255;
    __shared__ float wsh[KK];
    const int t = threadIdx.x;

    // Kernel generation: tap o = t/16, lane chunk = (t%16)*16 channels.
    if (t < 144) {
        const int o  = t >> 4;                          // 0..8
        const int ch = (t & 15) << 4;                   // 0,16,...,240
        const int og = c * KK + o;                      // global output row
        const float4* wr = (const float4*)(Wk + (size_t)og * C_ + ch);
        const float4* pr = (const float4*)(pooled + b * C_ + ch);
        float s = 0.f;
        #pragma unroll
        for (int i = 0; i < 4; ++i) {
            float4 w = wr[i];
            float4 p = pr[i];
            s += w.x * p.x + w.y * p.y + w.z * p.z + w.w * p.w;
        }
        #pragma unroll
        for (int off = 8; off > 0; off >>= 1)           // reduce 16-lane groups
            s += __shfl_down(s, off, 16);
        if ((t & 15) == 0)
            wsh[o] = fmaxf(s + bk[og], 0.f);
    }
    __syncthreads();

    const float w0 = wsh[0], w1 = wsh[1], w2 = wsh[2],
                w3 = wsh[3], w4 = wsh[4], w5 = wsh[5],
                w6 = wsh[6], w7 = wsh[7], w8 = wsh[8];

    const float* xp = x + (size_t)plane * HW;
    float* op = out + (size_t)plane * HW;

    // 2x4 output tiles: i in [0,392); rp = row pair, c0 = col base.
    for (int i = t; i < 392; i += 256) {
        const int rp = i / 14;                          // out rows 2rp, 2rp+1
        const int c0 = (i % 14) * 4;                    // 0,4,...,52
        const bool cl = (c0 > 0);
        const bool cr = (c0 < 52);

        float a00 = 0.f, a01 = 0.f, a02 = 0.f, a03 = 0.f;   // out row 2rp
        float a10 = 0.f, a11 = 0.f, a12 = 0.f, a13 = 0.f;   // out row 2rp+1

        // ---- input row 2rp-1 (taps w0..w2 -> row0) ----
        {
            const int r = 2 * rp - 1;
            const float* rw = xp + (r < 0 ? 0 : r) * W_;     // clamped, in-bounds
            float4 m = *(const float4*)(rw + c0);
            float vl = cl ? rw[c0 - 1] : 0.f;
            float vr = cr ? rw[c0 + 4] : 0.f;
            if (r < 0) { m.x = 0.f; m.y = 0.f; m.z = 0.f; m.w = 0.f; vl = 0.f; vr = 0.f; }
            a00 += w0 * vl  + w1 * m.x + w2 * m.y;
            a01 += w0 * m.x + w1 * m.y + w2 * m.z;
            a02 += w0 * m.y + w1 * m.z + w2 * m.w;
            a03 += w0 * m.z + w1 * m.w + w2 * vr;
        }
        // ---- input row 2rp (w3..w5 -> row0, w0..w2 -> row1) ----
        {
            const float* rw = xp + (2 * rp) * W_;
            float4 m = *(const float4*)(rw + c0);
            float vl = cl ? rw[c0 - 1] : 0.f;
            float vr = cr ? rw[c0 + 4] : 0.f;
            a00 += w3 * vl  + w4 * m.x + w5 * m.y;
            a01 += w3 * m.x + w4 * m.y + w5 * m.z;
            a02 += w3 * m.y + w4 * m.z + w5 * m.w;
            a03 += w3 * m.z + w4 * m.w + w5 * vr;
            a10 += w0 * vl  + w1 * m.x + w2 * m.y;
            a11 += w0 * m.x + w1 * m.y + w2 * m.z;
            a12 += w0 * m.y + w1 * m.z + w2 * m.w;
            a13 += w0 * m.z + w1 * m.w + w2 * vr;
        }
        // ---- input row 2rp+1 (w6..w8 -> row0, w3..w5 -> row1) ----
        {
            const float* rw = xp + (2 * rp + 1) * W_;
            float4 m = *(const float4*)(rw + c0);
            float vl = cl ? rw[c0 - 1] : 0.f;
            float vr = cr ? rw[c0 + 4] : 0.f;
            a00 += w6 * vl  + w7 * m.x + w8 * m.y;
            a01 += w6 * m.x + w7 * m.y + w8 * m.z;
            a02 += w6 * m.y + w7 * m.z + w8 * m.w;
            a03 += w6 * m.z + w7 * m.w + w8 * vr;
            a10 += w3 * vl  + w4 * m.x + w5 * m.y;
            a11 += w3 * m.x + w4 * m.y + w5 * m.z;
            a12 += w3 * m.y + w4 * m.z + w5 * m.w;
            a13 += w3 * m.z + w4 * m.w + w5 * vr;
        }
        // ---- input row 2rp+2 (w6..w8 -> row1) ----
        {
            const int r = 2 * rp + 2;
            const float* rw = xp + (r > 55 ? 55 : r) * W_;   // clamped, in-bounds
            float4 m = *(const float4*)(rw + c0);
            float vl = cl ? rw[c0 - 1] : 0.f;
            float vr = cr ? rw[c0 + 4] : 0.f;
            if (r > 55) { m.x = 0.f; m.y = 0.f; m.z = 0.f; m.w = 0.f; vl = 0.f; vr = 0.f; }
            a10 += w6 * vl  + w7 * m.x + w8 * m.y;
            a11 += w6 * m.x + w7 * m.y + w8 * m.z;
            a12 += w6 * m.y + w7 * m.z + w8 * m.w;
            a13 += w6 * m.z + w7 * m.w + w8 * vr;
        }

        v4f t0, t1;
        t0.x = a00; t0.y = a01; t0.z = a02; t0.w = a03;
        t1.x = a10; t1.y = a11; t1.z = a12; t1.w = a13;
        __builtin_nontemporal_store(t0, (v4f*)(op + (2 * rp + 0) * W_ + c0));
        __builtin_nontemporal_store(t1, (v4f*)(op + (2 * rp + 1) * W_ + c0));
    }
}

extern "C" void kernel_launch(void* const* d_in, const int* in_sizes, int n_in,
                              void* d_out, int out_size, void* d_ws, size_t ws_size,
                              hipStream_t stream) {
    const float* x  = (const float*)d_in[0];   // [B,C,H,W]
    const float* Wk = (const float*)d_in[1];   // [C*K*K, C]
    const float* bk = (const float*)d_in[2];   // [C*K*K]
    float* out = (float*)d_out;                // [B,C,H,W]

    float* pooled = (float*)d_ws;              // B*C = 8192 floats

    pool_kernel<<<NPLANES / 4, 256, 0, stream>>>(x, pooled);
    dconv_kernel<<<NPLANES, 256, 0, stream>>>(x, pooled, Wk, bk, out);
}

// Round 3
// 198.490 us; speedup vs baseline: 1.1145x; 1.1145x over previous
//
#include <hip/hip_runtime.h>

#define B_  32
#define C_  256
#define H_  56
#define W_  56
#define HW  3136      // H_*W_
#define KK  9
#define NPLANES (B_*C_)   // 8192

typedef float v4f __attribute__((ext_vector_type(4)));

// ---------------------------------------------------------------------------
// Kernel 1: global average pool. One WAVE per (b,c) plane, 4 planes/block.
// Pure shuffle reduction; regular loads keep x resident in L3 for dconv.
// At the HBM read floor (~17 us) — unchanged.
// ---------------------------------------------------------------------------
__global__ __launch_bounds__(256) void pool_kernel(const float* __restrict__ x,
                                                   float* __restrict__ pooled) {
    const int wid  = threadIdx.x >> 6;
    const int lane = threadIdx.x & 63;
    const int plane = blockIdx.x * 4 + wid;             // 2048 blocks * 4 waves
    const float4* xp = (const float4*)(x + (size_t)plane * HW);

    float s = 0.f;
    #pragma unroll
    for (int k = 0; k < 12; ++k) {                      // 12*64 = 768 strips
        float4 v = xp[lane + k * 64];
        s += (v.x + v.y) + (v.z + v.w);
    }
    if (lane < 16) {                                    // remainder 768..783
        float4 v = xp[768 + lane];
        s += (v.x + v.y) + (v.z + v.w);
    }
    #pragma unroll
    for (int off = 32; off > 0; off >>= 1)
        s += __shfl_down(s, off, 64);
    if (lane == 0)
        pooled[plane] = s * (1.0f / (float)HW);
}

// ---------------------------------------------------------------------------
// Kernel 2: register stencil, shuffle halos, zero scalar loads.
//   * kerngen (threads 0..143) -> 9 taps in 36B LDS, ONE barrier (verified).
//   * tile map: lane=(g,k), k<14 active, rp = half*16 + wave*4 + g.
//     Row groups never straddle a 16-lane boundary -> left/right halo comes
//     from __shfl_up/down(.,1,16)  (DPP row_shr/shl — pure VALU, no memory).
//   * per 2x4 tile: 4 dwordx4 loads + 8 shuffles   (was 4 vec + 8 scalar
//     global loads = ~230 L1 segments -> now ~80). TA/L1-pipe pressure /3.
//   * regular stores (not NT): L2 merges the even/odd-row split 64B lines,
//     WRITE_SIZE 137.5 -> ~103 MB.
// ---------------------------------------------------------------------------
__global__ __launch_bounds__(256, 8) void dconv_kernel(const float* __restrict__ x,
                                                       const float* __restrict__ pooled,
                                                       const float* __restrict__ Wk,
                                                       const float* __restrict__ bk,
                                                       float* __restrict__ out) {
    const int plane = blockIdx.x;                       // b*C_ + c
    const int b = plane >> 8;
    const int c = plane & 255;
    __shared__ float wsh[KK];
    const int t = threadIdx.x;

    // Kernel generation: tap o = t/16, lane chunk = (t%16)*16 channels.
    if (t < 144) {
        const int o  = t >> 4;                          // 0..8
        const int ch = (t & 15) << 4;                   // 0,16,...,240
        const int og = c * KK + o;                      // global output row
        const float4* wr = (const float4*)(Wk + (size_t)og * C_ + ch);
        const float4* pr = (const float4*)(pooled + b * C_ + ch);
        float s = 0.f;
        #pragma unroll
        for (int i = 0; i < 4; ++i) {
            float4 w = wr[i];
            float4 p = pr[i];
            s += w.x * p.x + w.y * p.y + w.z * p.z + w.w * p.w;
        }
        #pragma unroll
        for (int off = 8; off > 0; off >>= 1)           // reduce 16-lane groups
            s += __shfl_down(s, off, 16);
        if ((t & 15) == 0)
            wsh[o] = fmaxf(s + bk[og], 0.f);
    }
    __syncthreads();

    const float w0 = wsh[0], w1 = wsh[1], w2 = wsh[2],
                w3 = wsh[3], w4 = wsh[4], w5 = wsh[5],
                w6 = wsh[6], w7 = wsh[7], w8 = wsh[8];

    const float* xp = x + (size_t)plane * HW;
    float* op = out + (size_t)plane * HW;

    const int lane = t & 63;
    const int k    = lane & 15;                         // column group: k*4
    const int g    = lane >> 4;                         // row-pair group in wave
    const int wv   = t >> 6;                            // wave id 0..3
    const bool ka  = (k < 14);                          // cols 0..55
    const int c0   = ka ? (k << 2) : 0;                 // clamp idle lanes in-bounds
    const bool hl  = (k > 0);                           // has in-row left neighbor
    const bool hr  = (k < 13);                          // has in-row right neighbor

    #pragma unroll
    for (int half = 0; half < 2; ++half) {
        const int rp = half * 16 + wv * 4 + g;          // 0..15, then 16..31
        if (rp >= 28) break;                            // wave-uniform (wv=3,half=1)

        const int rA = (rp == 0)  ? 0  : 2 * rp - 1;    // row above (clamped)
        const int rB = (rp == 27) ? 55 : 2 * rp + 2;    // row below (clamped)

        float4 A  = *(const float4*)(xp + rA * W_ + c0);
        float4 M  = *(const float4*)(xp + (2 * rp) * W_ + c0);
        float4 N  = *(const float4*)(xp + (2 * rp + 1) * W_ + c0);
        float4 Bv = *(const float4*)(xp + rB * W_ + c0);
        if (rp == 0)  { A.x = 0.f;  A.y = 0.f;  A.z = 0.f;  A.w = 0.f; }
        if (rp == 27) { Bv.x = 0.f; Bv.y = 0.f; Bv.z = 0.f; Bv.w = 0.f; }

        if (ka) {
            // halo columns from neighbor lanes (16-lane groups => DPP)
            float Al = __shfl_up(A.w, 1, 16),  Ar = __shfl_down(A.x, 1, 16);
            float Ml = __shfl_up(M.w, 1, 16),  Mr = __shfl_down(M.x, 1, 16);
            float Nl = __shfl_up(N.w, 1, 16),  Nr = __shfl_down(N.x, 1, 16);
            float Bl = __shfl_up(Bv.w, 1, 16), Br = __shfl_down(Bv.x, 1, 16);
            Al = hl ? Al : 0.f;  Ml = hl ? Ml : 0.f;
            Nl = hl ? Nl : 0.f;  Bl = hl ? Bl : 0.f;
            Ar = hr ? Ar : 0.f;  Mr = hr ? Mr : 0.f;
            Nr = hr ? Nr : 0.f;  Br = hr ? Br : 0.f;

            v4f t0, t1;
            t0.x = w0*Al  + w1*A.x  + w2*A.y  + w3*Ml  + w4*M.x  + w5*M.y  + w6*Nl  + w7*N.x  + w8*N.y;
            t0.y = w0*A.x + w1*A.y  + w2*A.z  + w3*M.x + w4*M.y  + w5*M.z  + w6*N.x + w7*N.y  + w8*N.z;
            t0.z = w0*A.y + w1*A.z  + w2*A.w  + w3*M.y + w4*M.z  + w5*M.w  + w6*N.y + w7*N.z  + w8*N.w;
            t0.w = w0*A.z + w1*A.w  + w2*Ar   + w3*M.z + w4*M.w  + w5*Mr   + w6*N.z + w7*N.w  + w8*Nr;
            t1.x = w0*Ml  + w1*M.x  + w2*M.y  + w3*Nl  + w4*N.x  + w5*N.y  + w6*Bl  + w7*Bv.x + w8*Bv.y;
            t1.y = w0*M.x + w1*M.y  + w2*M.z  + w3*N.x + w4*N.y  + w5*N.z  + w6*Bv.x+ w7*Bv.y + w8*Bv.z;
            t1.z = w0*M.y + w1*M.z  + w2*M.w  + w3*N.y + w4*N.z  + w5*N.w  + w6*Bv.y+ w7*Bv.z + w8*Bv.w;
            t1.w = w0*M.z + w1*M.w  + w2*Mr   + w3*N.z + w4*N.w  + w5*Nr   + w6*Bv.z+ w7*Bv.w + w8*Br;

            *(v4f*)(op + (2 * rp + 0) * W_ + c0) = t0;  // regular stores: L2 merges
            *(v4f*)(op + (2 * rp + 1) * W_ + c0) = t1;
        }
    }
}

extern "C" void kernel_launch(void* const* d_in, const int* in_sizes, int n_in,
                              void* d_out, int out_size, void* d_ws, size_t ws_size,
                              hipStream_t stream) {
    const float* x  = (const float*)d_in[0];   // [B,C,H,W]
    const float* Wk = (const float*)d_in[1];   // [C*K*K, C]
    const float* bk = (const float*)d_in[2];   // [C*K*K]
    float* out = (float*)d_out;                // [B,C,H,W]

    float* pooled = (float*)d_ws;              // B*C = 8192 floats

    pool_kernel<<<NPLANES / 4, 256, 0, stream>>>(x, pooled);
    dconv_kernel<<<NPLANES, 256, 0, stream>>>(x, pooled, Wk, bk, out);
}